// Round 1
// baseline (143.876 us; speedup 1.0000x reference)
//
#include <hip/hip_runtime.h>

// SoftMinLayer: sliding-window squared distance + softmin-weighted pooling.
// input_seqs: (512, 1024) f32, shapelets: (100, 50) f32 -> out (512, 100) f32.
// D[i,j,k] = (sq_win[i,j] - 2*cross[i,j,k] + ssq[k]) / L
// M[i,k]   = sum_j Dm*exp(ALPHA*Dm) / sum_j exp(ALPHA*Dm),  Dm = D - min_j D

#define N_SEQ   512
#define Q_LEN   1024
#define K_SH    100
#define L_SH    50
#define J_WIN   (Q_LEN - L_SH)   // 974
#define ALPHA_F (-100.0f)

// 4-way j-split: quarter boundaries are multiples of 4 so float4 LDS loads align.
#define J_STEP  244              // quarters: [0,244) [244,488) [488,732) [732,974)

__global__ __launch_bounds__(512, 2)
void softmin_shapelet_kernel(const float* __restrict__ x,
                             const float* __restrict__ sh,
                             float* __restrict__ out) {
    __shared__ __align__(16) float lds_x[Q_LEN];
    __shared__ float lds_sqw[J_WIN + 2];
    __shared__ float red_m[512], red_S[512], red_T[512];

    const int i       = blockIdx.x;
    const int tid     = threadIdx.x;
    const int k       = tid & 127;   // shapelet index (active if < 100)
    const int quarter = tid >> 7;    // j-range partition 0..3

    // ---- stage x row into LDS (coalesced float4) ----
    {
        const float4* gx = (const float4*)(x + (size_t)i * Q_LEN);
        float4*       lx = (float4*)lds_x;
        if (tid < Q_LEN / 4) lx[tid] = gx[tid];
    }
    __syncthreads();

    // ---- sq_win[j] = sum_{l<50} x[j+l]^2 (direct sum, fp32) ----
    for (int j = tid; j < J_WIN; j += 512) {
        float a = 0.f;
        #pragma unroll
        for (int l = 0; l < L_SH; ++l) {
            float v = lds_x[j + l];
            a = fmaf(v, v, a);
        }
        lds_sqw[j] = a;
    }

    // ---- shapelet row k into registers + its squared norm ----
    float s_reg[L_SH];
    float ssq = 0.f;
    if (k < K_SH) {
        const float2* s2 = (const float2*)(sh + (size_t)k * L_SH); // 8B aligned (k*200)
        #pragma unroll
        for (int q = 0; q < L_SH / 2; ++q) {
            float2 v = s2[q];
            s_reg[2 * q]     = v.x;
            s_reg[2 * q + 1] = v.y;
            ssq = fmaf(v.x, v.x, ssq);
            ssq = fmaf(v.y, v.y, ssq);
        }
    }
    __syncthreads();

    // ---- online softmin over this thread's j-range ----
    float m = 1e30f, S = 0.f, T = 0.f;
    if (k < K_SH) {
        const int jlo = quarter * J_STEP;
        const int jhi = (jlo + J_STEP < J_WIN) ? (jlo + J_STEP) : J_WIN;
        const float4* lx4 = (const float4*)lds_x;

        int j0 = jlo;
        for (; j0 + 4 <= jhi; j0 += 4) {
            // cross-correlation for j0..j0+3 against s_reg (200 FMAs, 14 b128 broadcasts)
            float acc0 = 0.f, acc1 = 0.f, acc2 = 0.f, acc3 = 0.f;
            const int f0 = j0 >> 2;
            #pragma unroll
            for (int q = 0; q < 14; ++q) {
                float4 xv = lx4[f0 + q];
                float xs[4] = {xv.x, xv.y, xv.z, xv.w};
                #pragma unroll
                for (int c = 0; c < 4; ++c) {
                    const int p = 4 * q + c;           // x offset within chunk
                    if (p - 0 >= 0 && p - 0 < L_SH) acc0 = fmaf(xs[c], s_reg[p - 0], acc0);
                    if (p - 1 >= 0 && p - 1 < L_SH) acc1 = fmaf(xs[c], s_reg[p - 1], acc1);
                    if (p - 2 >= 0 && p - 2 < L_SH) acc2 = fmaf(xs[c], s_reg[p - 2], acc2);
                    if (p - 3 >= 0 && p - 3 < L_SH) acc3 = fmaf(xs[c], s_reg[p - 3], acc3);
                }
            }
            float accs[4] = {acc0, acc1, acc2, acc3};
            #pragma unroll
            for (int d = 0; d < 4; ++d) {
                const int j = j0 + d;
                const float dv = (lds_sqw[j] - 2.f * accs[d] + ssq) * (1.f / (float)L_SH);
                if (dv < m) {       // new running min: rescale prior sums
                    const float sc = __expf(ALPHA_F * (m - dv));
                    T = (T + (m - dv) * S) * sc;       // new term contributes 0 to T
                    S = S * sc + 1.f;                  // new term weight = 1
                    m = dv;
                } else {
                    const float t = dv - m;
                    const float w = __expf(ALPHA_F * t);
                    S += w;
                    T = fmaf(t, w, T);
                }
            }
        }
        // tail (quarter 3: j = 972, 973)
        for (int j = j0; j < jhi; ++j) {
            float a = 0.f;
            #pragma unroll
            for (int l = 0; l < L_SH; ++l) a = fmaf(lds_x[j + l], s_reg[l], a);
            const float dv = (lds_sqw[j] - 2.f * a + ssq) * (1.f / (float)L_SH);
            if (dv < m) {
                const float sc = __expf(ALPHA_F * (m - dv));
                T = (T + (m - dv) * S) * sc;
                S = S * sc + 1.f;
                m = dv;
            } else {
                const float t = dv - m;
                const float w = __expf(ALPHA_F * t);
                S += w;
                T = fmaf(t, w, T);
            }
        }
    }

    // ---- merge the 4 j-partitions per k ----
    red_m[tid] = m; red_S[tid] = S; red_T[tid] = T;
    __syncthreads();

    if (quarter == 0 && k < K_SH) {
        #pragma unroll
        for (int q = 1; q < 4; ++q) {
            const float m1 = red_m[tid + 128 * q];
            const float S1 = red_S[tid + 128 * q];
            const float T1 = red_T[tid + 128 * q];
            const float mm = fminf(m, m1);
            const float e0 = __expf(ALPHA_F * (m - mm));
            const float e1 = __expf(ALPHA_F * (m1 - mm));
            T = (T + (m - mm) * S) * e0 + (T1 + (m1 - mm) * S1) * e1;
            S = S * e0 + S1 * e1;
            m = mm;
        }
        out[(size_t)i * K_SH + k] = T / S;
    }
}

extern "C" void kernel_launch(void* const* d_in, const int* in_sizes, int n_in,
                              void* d_out, int out_size, void* d_ws, size_t ws_size,
                              hipStream_t stream) {
    const float* x  = (const float*)d_in[0];   // (512, 1024) f32
    const float* sh = (const float*)d_in[1];   // (100, 50)  f32
    float* out = (float*)d_out;                // (512, 100) f32

    softmin_shapelet_kernel<<<N_SEQ, 512, 0, stream>>>(x, sh, out);
}

// Round 2
// 128.221 us; speedup vs baseline: 1.1221x; 1.1221x over previous
//
#include <hip/hip_runtime.h>

// SoftMinLayer: sliding-window squared distance + softmin-weighted pooling.
// input_seqs: (512, 1024) f32, shapelets: (100, 50) f32 -> out (512, 100) f32.
// D[i,j,k] = (sq_win[i,j] - 2*cross[i,j,k] + ssq[k]) / L
// M[i,k]   = sum_j Dm*exp(ALPHA*Dm) / sum_j exp(ALPHA*Dm),  Dm = D - min_j D
//
// R2: 8-j chunks, batched softmin update guarded by chunk-min threshold
// (terms with dv - m > 0.5 weigh < e^-50 — numerically zero), branchless
// update when taken. Cuts the per-j divergent exp/branch overhead that made
// R1 2.6x the FMA floor.

#define N_SEQ   512
#define Q_LEN   1024
#define K_SH    100
#define L_SH    50
#define J_WIN   (Q_LEN - L_SH)   // 974
#define ALPHA_F (-100.0f)
#define SKIP_T  0.5f             // exp(-100*0.5)=2e-22: negligible vs S>=1

// 4-way j-split; boundaries multiples of 4 for float4 LDS alignment.
#define J_STEP  244              // quarters: [0,244) [244,488) [488,732) [732,974)

__device__ __forceinline__ void softmin_upd(float dv, float& m, float& S, float& T) {
    const float nm = fminf(m, dv);
    const float sc = __expf(ALPHA_F * (m - nm));   // 1 if m unchanged; 0 on first hit
    T = (T + (m - nm) * S) * sc;
    S = S * sc;
    m = nm;
    const float t = dv - m;
    const float w = __expf(ALPHA_F * t);
    S += w;
    T = fmaf(t, w, T);
}

__global__ __launch_bounds__(512, 4)
void softmin_shapelet_kernel(const float* __restrict__ x,
                             const float* __restrict__ sh,
                             float* __restrict__ out) {
    __shared__ __align__(16) float lds_x[Q_LEN];
    __shared__ __align__(16) float lds_sqw[J_WIN + 2];   // 976 floats = 244 float4
    __shared__ float red_m[512], red_S[512], red_T[512];

    const int i       = blockIdx.x;
    const int tid     = threadIdx.x;
    const int k       = tid & 127;   // shapelet index (active if < 100)
    const int quarter = tid >> 7;    // j-range partition 0..3

    // ---- stage x row into LDS (coalesced float4) ----
    {
        const float4* gx = (const float4*)(x + (size_t)i * Q_LEN);
        float4*       lx = (float4*)lds_x;
        if (tid < Q_LEN / 4) lx[tid] = gx[tid];
    }
    __syncthreads();

    // ---- sq_win[j] = sum_{l<50} x[j+l]^2 (direct sum, fp32) ----
    for (int j = tid; j < J_WIN; j += 512) {
        float a = 0.f;
        #pragma unroll
        for (int l = 0; l < L_SH; ++l) {
            float v = lds_x[j + l];
            a = fmaf(v, v, a);
        }
        lds_sqw[j] = a;
    }

    // ---- shapelet row k into registers + its squared norm ----
    float s_reg[L_SH];
    float ssq = 0.f;
    if (k < K_SH) {
        const float2* s2 = (const float2*)(sh + (size_t)k * L_SH); // 8B aligned
        #pragma unroll
        for (int q = 0; q < L_SH / 2; ++q) {
            float2 v = s2[q];
            s_reg[2 * q]     = v.x;
            s_reg[2 * q + 1] = v.y;
            ssq = fmaf(v.x, v.x, ssq);
            ssq = fmaf(v.y, v.y, ssq);
        }
    }
    __syncthreads();

    // ---- online softmin over this thread's j-range, 8 j per chunk ----
    float m = 1e30f, S = 0.f, T = 0.f;
    if (k < K_SH) {
        const int jlo = quarter * J_STEP;
        const int jhi = (jlo + J_STEP < J_WIN) ? (jlo + J_STEP) : J_WIN;
        const float4* lx4  = (const float4*)lds_x;
        const float4* sqw4 = (const float4*)lds_sqw;
        const float base = ssq * (1.f / (float)L_SH);  // dv = fma(a,-2/L, fma(sqw,1/L, base))

        int j0 = jlo;
        for (; j0 + 8 <= jhi; j0 += 8) {
            // cross-correlation for j0..j0+7 (400 FMAs, 15 b128 broadcasts)
            float acc[8] = {0.f, 0.f, 0.f, 0.f, 0.f, 0.f, 0.f, 0.f};
            const int f0 = j0 >> 2;
            #pragma unroll
            for (int q = 0; q < 15; ++q) {
                float4 xv = lx4[f0 + q];
                float xs[4] = {xv.x, xv.y, xv.z, xv.w};
                #pragma unroll
                for (int c = 0; c < 4; ++c) {
                    const int p = 4 * q + c;   // x offset within chunk window
                    #pragma unroll
                    for (int d = 0; d < 8; ++d) {
                        if (p - d >= 0 && p - d < L_SH)
                            acc[d] = fmaf(xs[c], s_reg[p - d], acc[d]);
                    }
                }
            }
            // distances
            const float4 sqa = sqw4[f0];
            const float4 sqb = sqw4[f0 + 1];
            float dv[8];
            dv[0] = fmaf(acc[0], -2.f / L_SH, fmaf(sqa.x, 1.f / L_SH, base));
            dv[1] = fmaf(acc[1], -2.f / L_SH, fmaf(sqa.y, 1.f / L_SH, base));
            dv[2] = fmaf(acc[2], -2.f / L_SH, fmaf(sqa.z, 1.f / L_SH, base));
            dv[3] = fmaf(acc[3], -2.f / L_SH, fmaf(sqa.w, 1.f / L_SH, base));
            dv[4] = fmaf(acc[4], -2.f / L_SH, fmaf(sqb.x, 1.f / L_SH, base));
            dv[5] = fmaf(acc[5], -2.f / L_SH, fmaf(sqb.y, 1.f / L_SH, base));
            dv[6] = fmaf(acc[6], -2.f / L_SH, fmaf(sqb.z, 1.f / L_SH, base));
            dv[7] = fmaf(acc[7], -2.f / L_SH, fmaf(sqb.w, 1.f / L_SH, base));
            // chunk min
            float cmin = fminf(fminf(fminf(dv[0], dv[1]), fminf(dv[2], dv[3])),
                               fminf(fminf(dv[4], dv[5]), fminf(dv[6], dv[7])));
            // skip whole update if nothing in this chunk can matter
            // (all-lane skip -> s_cbranch_execz past 9 exps + ~35 ops)
            if (cmin < m + SKIP_T) {
                const float nm = fminf(m, cmin);
                const float sc = __expf(ALPHA_F * (m - nm));
                T = (T + (m - nm) * S) * sc;
                S = S * sc;
                m = nm;
                #pragma unroll
                for (int d = 0; d < 8; ++d) {
                    const float t = dv[d] - m;
                    const float w = __expf(ALPHA_F * t);
                    S += w;
                    T = fmaf(t, w, T);
                }
            }
        }
        // tail (quarter 3: j = 972, 973)
        for (int j = j0; j < jhi; ++j) {
            float a = 0.f;
            #pragma unroll
            for (int l = 0; l < L_SH; ++l) a = fmaf(lds_x[j + l], s_reg[l], a);
            const float dvs = fmaf(a, -2.f / L_SH, fmaf(lds_sqw[j], 1.f / L_SH, base));
            if (dvs < m + SKIP_T) softmin_upd(dvs, m, S, T);
        }
    }

    // ---- merge the 4 j-partitions per k ----
    red_m[tid] = m; red_S[tid] = S; red_T[tid] = T;
    __syncthreads();

    if (quarter == 0 && k < K_SH) {
        #pragma unroll
        for (int q = 1; q < 4; ++q) {
            const float m1 = red_m[tid + 128 * q];
            const float S1 = red_S[tid + 128 * q];
            const float T1 = red_T[tid + 128 * q];
            const float mm = fminf(m, m1);
            const float e0 = __expf(ALPHA_F * (m - mm));
            const float e1 = __expf(ALPHA_F * (m1 - mm));
            T = (T + (m - mm) * S) * e0 + (T1 + (m1 - mm) * S1) * e1;
            S = S * e0 + S1 * e1;
            m = mm;
        }
        out[(size_t)i * K_SH + k] = T / S;
    }
}

extern "C" void kernel_launch(void* const* d_in, const int* in_sizes, int n_in,
                              void* d_out, int out_size, void* d_ws, size_t ws_size,
                              hipStream_t stream) {
    const float* x  = (const float*)d_in[0];   // (512, 1024) f32
    const float* sh = (const float*)d_in[1];   // (100, 50)  f32
    float* out = (float*)d_out;                // (512, 100) f32

    softmin_shapelet_kernel<<<N_SEQ, 512, 0, stream>>>(x, sh, out);
}